// Round 8
// baseline (929.901 us; speedup 1.0000x reference)
//
#include <hip/hip_runtime.h>
#include <hip/hip_cooperative_groups.h>

namespace cg = cooperative_groups;

#define GN   1024
#define GNN  (GN * GN)
#define GP   16
#define NOUT 127          // ys[1:] = T_1 .. T_127
#define TILE 64           // output tile per block
#define KST  16           // fused time steps per phase
#define NPH  8            // phases (8*16 = 128 >= 127)
#define SZ   96           // TILE + 2*KST (region side)
#define NRB  24           // row-blocks  (SZ/4)
#define NCB  24           // col-blocks  (SZ/4)
#define NTHR 576          // NRB*NCB threads, 9 waves
#define RST  100          // plane row stride (floats), 4-float aligned
#define AXB  (NRB * 2 * RST)            // aux base within plane = 4800
#define AXS  ((NCB + 1) * RST)          // one aux side = 2500
#define PLN  (AXB + 2 * AXS)            // plane floats = 9800 (39.2 KB)

// Exact fp32 constants: DT/dx^2 = 1e-7*1023^2 = 0.1046529, DT/(2dx) = 5.115e-5

__device__ __forceinline__ void coord16(int t, int& c0, int& c1, float& w) {
    // coords = linspace(0, 15, 1024): c = t * 15/1023
    double c = (double)t * (15.0 / 1023.0);
    c0 = (int)c;
    c1 = c0 + 1 > 15 ? 15 : c0 + 1;
    w  = (float)(c - (double)c0);
}

__device__ __forceinline__ float bilin16(const float* __restrict__ m,
                                         int i0, int i1, float wi,
                                         int j0, int j1, float wj) {
    float m00 = m[i0 * GP + j0];
    float m10 = m[i1 * GP + j0];
    float m01 = m[i0 * GP + j1];
    float m11 = m[i1 * GP + j1];
    float r0 = m00 * (1.0f - wi) + m10 * wi;
    float r1 = m01 * (1.0f - wi) + m11 * wi;
    return r0 * (1.0f - wj) + r1 * wj;
}

__device__ __forceinline__ float cellv(float C, float L, float R, float U, float D,
                                       float a2, float k2) {
    // val = C - k2*C*((D-U)+(R-L)) + a2*(U+D+L+R-4C)
    float s   = (D - U) + (R - L);
    float lap = fmaf(-4.0f, C, (U + D) + (L + R));
    return fmaf(a2, lap, fmaf(-k2, C * s, C));
}

// One 4-wide row of cells: verified column shift-select logic (rounds 4-7).
__device__ __forceinline__ float4 rowcell(float4 v, float4 U, float4 D,
                                          float sl, float sr,
                                          float4 a2, float4 k2,
                                          bool isl, bool isr) {
    float L0 = isl ? v.x : sl;
    float C0 = isl ? v.y : v.x;
    float R0 = isl ? v.z : v.y;
    float U0 = isl ? U.y : U.x;
    float D0 = isl ? D.y : D.x;
    float L3 = isr ? v.y : v.z;
    float C3 = isr ? v.z : v.w;
    float R3 = isr ? v.w : sr;
    float U3 = isr ? U.z : U.w;
    float D3 = isr ? D.z : D.w;
    float4 nv;
    nv.x = cellv(C0,  L0,  R0,  U0,  D0,  a2.x, k2.x);
    nv.y = cellv(v.y, v.x, v.z, U.y, D.y, a2.y, k2.y);
    nv.z = cellv(v.z, v.y, v.w, U.z, D.z, a2.z, k2.z);
    nv.w = cellv(C3,  L3,  R3,  U3,  D3,  a2.w, k2.w);
    return nv;
}

// LDS-only barrier (global stores stay in flight; rule #18 fencing).
__device__ __forceinline__ void lds_barrier() {
    __builtin_amdgcn_sched_barrier(0);
    asm volatile("s_waitcnt lgkmcnt(0)" ::: "memory");
    __builtin_amdgcn_s_barrier();
    __builtin_amdgcn_sched_barrier(0);
}

// ---------------------------------------------------------------------------
// Cooperative single-launch kernel: 8 phases x 16 steps, grid.sync between
// phases. Verified stale-halo machinery (rounds 4-7). At phase boundaries,
// core threads' register carry V and plane-0 LDS entries are already exact
// (stored slab values equal the post-replica NVs — value-identical to the
// relaunch seeding); only halo threads reload from the previous slab.
// Cross-XCD visibility: __threadfence (agent release: wb L2) before
// grid.sync, acquire fence after; slab addresses are phase-unique.
// ---------------------------------------------------------------------------
__global__ __launch_bounds__(NTHR)
void coop_steps_kernel(const float* __restrict__ u0,
                       const float* __restrict__ alpha,
                       const float* __restrict__ kappa,
                       float* __restrict__ out)
{
    __shared__ float lds[2][PLN];   // 2 x 39.2 KB

    const int tid = threadIdx.x;
    const int rb  = tid / NCB;
    const int cb  = tid - rb * NCB;
    const int r0  = rb * 4;
    const int c4  = cb * 4;

    const int gi0 = blockIdx.y * TILE;
    const int gj0 = blockIdx.x * TILE;
    int oi = gi0 - KST; oi = oi < 0 ? 0 : (oi > GN - SZ ? GN - SZ : oi);
    int oj = gj0 - KST; oj = oj < 0 ? 0 : (oj > GN - SZ ? GN - SZ : oj);
    const int di = gi0 - oi;
    const int dj = gj0 - oj;

    const bool istop = (rb == 0), isbot = (rb == NRB - 1);
    const bool isl   = (cb == 0), isr   = (cb == NCB - 1);
    const bool core  = (rb >= (di >> 2)) && (rb < (di >> 2) + 16)
                    && (cb >= (dj >> 2)) && (cb < (dj >> 2) + 16);

    const long gbase = (long)(oi + r0) * GN + oj + c4;

    const int uoff   = (istop ? 0 : (rb * 2 - 1)) * RST + c4;
    const int doff   = (isbot ? (NRB * 2 - 1) : (rb * 2 + 2)) * RST + c4;
    const int w0off  = (rb * 2) * RST + c4;
    const int w3off  = (rb * 2 + 1) * RST + c4;
    const int sloff  = AXB + cb * RST + rb * 4;
    const int wsloff = AXB + (cb + 1) * RST + rb * 4;
    const int sroff  = AXB + AXS + (cb + 1) * RST + rb * 4;
    const int wsroff = AXB + AXS + cb * RST + rb * 4;

    // Coefficients, computed ONCE for the whole run (inline bilinear path).
    float4 a2[4], k2[4];
    #pragma unroll
    for (int q = 0; q < 4; ++q) {
        int gi = oi + r0 + q;
        int ci = gi < 1 ? 1 : (gi > GN - 2 ? GN - 2 : gi);
        int i0, i1; float wi;
        coord16(ci, i0, i1, wi);
        float av[4], kv[4];
        #pragma unroll
        for (int u = 0; u < 4; ++u) {
            int gj = oj + c4 + u;
            int cj = gj < 1 ? 1 : (gj > GN - 2 ? GN - 2 : gj);
            int j0, j1; float wj;
            coord16(cj, j0, j1, wj);
            av[u] = bilin16(alpha, i0, i1, wi, j0, j1, wj) * 0.1046529f;
            kv[u] = bilin16(kappa, i0, i1, wi, j0, j1, wj) * 5.115e-5f;
        }
        a2[q] = make_float4(av[0], av[1], av[2], av[3]);
        k2[q] = make_float4(kv[0], kv[1], kv[2], kv[3]);
    }

    // Initial seed from u0 (raw rows to LDS, clamped rows to register carry).
    float4 V[4];
    {
        float4 ld0 = *(const float4*)(u0 + gbase);
        float4 ld1 = *(const float4*)(u0 + gbase + GN);
        float4 ld2 = *(const float4*)(u0 + gbase + 2 * GN);
        float4 ld3 = *(const float4*)(u0 + gbase + 3 * GN);
        *(float4*)&lds[0][w0off]  = ld0;
        *(float4*)&lds[0][w3off]  = ld3;
        *(float4*)&lds[0][wsloff] = make_float4(ld0.w, ld1.w, ld2.w, ld3.w);
        *(float4*)&lds[0][wsroff] = make_float4(ld0.x, ld1.x, ld2.x, ld3.x);
        V[0] = istop ? ld1 : ld0;
        V[1] = ld1;
        V[2] = ld2;
        V[3] = isbot ? ld2 : ld3;
    }
    __syncthreads();

    cg::grid_group g = cg::this_grid();

    #pragma unroll 1
    for (int phase = 0; phase < NPH; ++phase) {
        const int base = phase * KST;
        const int tmax = NOUT - base;

        if (phase) {
            __threadfence();          // release: write back dirty L2 (cross-XCD)
            g.sync();
            __threadfence();          // acquire: invalidate stale cached lines
            if (!core) {              // halo refresh from the previous slab
                const float* sp = out + (long)(base - 1) * GNN;
                float4 ld0 = *(const float4*)(sp + gbase);
                float4 ld1 = *(const float4*)(sp + gbase + GN);
                float4 ld2 = *(const float4*)(sp + gbase + 2 * GN);
                float4 ld3 = *(const float4*)(sp + gbase + 3 * GN);
                *(float4*)&lds[0][w0off]  = ld0;
                *(float4*)&lds[0][w3off]  = ld3;
                *(float4*)&lds[0][wsloff] = make_float4(ld0.w, ld1.w, ld2.w, ld3.w);
                *(float4*)&lds[0][wsroff] = make_float4(ld0.x, ld1.x, ld2.x, ld3.x);
                V[0] = istop ? ld1 : ld0;
                V[1] = ld1;
                V[2] = ld2;
                V[3] = isbot ? ld2 : ld3;
            }
            __syncthreads();
        }

        #pragma unroll 1
        for (int it = 0; it < KST / 2; ++it) {
            #pragma unroll
            for (int half = 0; half < 2; ++half) {
                const int t = 2 * it + 1 + half;
                const float* cur = half ? &lds[1][0] : &lds[0][0];
                float*       nxt = half ? &lds[0][0] : &lds[1][0];

                float4 U  = *(const float4*)(cur + uoff);
                float4 D  = *(const float4*)(cur + doff);
                float4 SL = *(const float4*)(cur + sloff);
                float4 SR = *(const float4*)(cur + sroff);

                float4 Uop1 = istop ? U : V[0];
                float4 Dop2 = isbot ? D : V[3];

                float4 NV0 = rowcell(V[0], U,    V[1], SL.x, SR.x, a2[0], k2[0], isl, isr);
                float4 NV1 = rowcell(V[1], Uop1, V[2], SL.y, SR.y, a2[1], k2[1], isl, isr);
                float4 NV2 = rowcell(V[2], V[1], Dop2, SL.z, SR.z, a2[2], k2[2], isl, isr);
                float4 NV3 = rowcell(V[3], V[2], D,    SL.w, SR.w, a2[3], k2[3], isl, isr);
                if (istop) NV0 = NV1;
                if (isbot) NV3 = NV2;

                *(float4*)(nxt + w0off)  = NV0;
                *(float4*)(nxt + w3off)  = NV3;
                *(float4*)(nxt + wsloff) = make_float4(NV0.w, NV1.w, NV2.w, NV3.w);
                *(float4*)(nxt + wsroff) = make_float4(NV0.x, NV1.x, NV2.x, NV3.x);

                if (core && t <= tmax) {
                    float* slab = out + (long)(base + t - 1) * GNN;
                    *(float4*)(slab + gbase)          = NV0;
                    *(float4*)(slab + gbase + GN)     = NV1;
                    *(float4*)(slab + gbase + 2 * GN) = NV2;
                    *(float4*)(slab + gbase + 3 * GN) = NV3;
                }
                V[0] = NV0; V[1] = NV1; V[2] = NV2; V[3] = NV3;
                lds_barrier();
            }
        }
    }
}

// ---------------------------------------------------------------------------
// Fallback path (round-7 verified kernels), used if cooperative launch is
// unavailable.
// ---------------------------------------------------------------------------
__global__ __launch_bounds__(256)
void resize_maps_kernel(const float* __restrict__ alpha,
                        const float* __restrict__ kappa,
                        float* __restrict__ a2map,
                        float* __restrict__ k2map) {
    int idx = blockIdx.x * 256 + threadIdx.x;
    if (idx >= GNN) return;
    int i = idx >> 10;
    int j = idx & (GN - 1);
    int ci = i < 1 ? 1 : (i > GN - 2 ? GN - 2 : i);
    int cj = j < 1 ? 1 : (j > GN - 2 ? GN - 2 : j);
    int i0, i1, j0, j1; float wi, wj;
    coord16(ci, i0, i1, wi);
    coord16(cj, j0, j1, wj);
    a2map[idx] = bilin16(alpha, i0, i1, wi, j0, j1, wj) * 0.1046529f;
    k2map[idx] = bilin16(kappa, i0, i1, wi, j0, j1, wj) * 5.115e-5f;
}

template <bool USE_WS>
__global__ __launch_bounds__(NTHR)
void fused_steps_kernel(const float* __restrict__ srcp,
                        const float* __restrict__ Aarg,
                        const float* __restrict__ Karg,
                        float* __restrict__ out,
                        int base)
{
    __shared__ float lds[2][PLN];

    const int tid = threadIdx.x;
    const int rb  = tid / NCB;
    const int cb  = tid - rb * NCB;
    const int r0  = rb * 4;
    const int c4  = cb * 4;

    const int gi0 = blockIdx.y * TILE;
    const int gj0 = blockIdx.x * TILE;
    int oi = gi0 - KST; oi = oi < 0 ? 0 : (oi > GN - SZ ? GN - SZ : oi);
    int oj = gj0 - KST; oj = oj < 0 ? 0 : (oj > GN - SZ ? GN - SZ : oj);
    const int di = gi0 - oi;
    const int dj = gj0 - oj;

    const bool istop = (rb == 0), isbot = (rb == NRB - 1);
    const bool isl   = (cb == 0), isr   = (cb == NCB - 1);
    const bool core  = (rb >= (di >> 2)) && (rb < (di >> 2) + 16)
                    && (cb >= (dj >> 2)) && (cb < (dj >> 2) + 16);
    const int  tmax  = NOUT - base;

    const long gbase = (long)(oi + r0) * GN + oj + c4;

    const int uoff   = (istop ? 0 : (rb * 2 - 1)) * RST + c4;
    const int doff   = (isbot ? (NRB * 2 - 1) : (rb * 2 + 2)) * RST + c4;
    const int w0off  = (rb * 2) * RST + c4;
    const int w3off  = (rb * 2 + 1) * RST + c4;
    const int sloff  = AXB + cb * RST + rb * 4;
    const int wsloff = AXB + (cb + 1) * RST + rb * 4;
    const int sroff  = AXB + AXS + (cb + 1) * RST + rb * 4;
    const int wsroff = AXB + AXS + cb * RST + rb * 4;

    float4 a2[4], k2[4];
    if (USE_WS) {
        #pragma unroll
        for (int q = 0; q < 4; ++q) {
            a2[q] = *(const float4*)(Aarg + gbase + q * GN);
            k2[q] = *(const float4*)(Karg + gbase + q * GN);
        }
    } else {
        #pragma unroll
        for (int q = 0; q < 4; ++q) {
            int gi = oi + r0 + q;
            int ci = gi < 1 ? 1 : (gi > GN - 2 ? GN - 2 : gi);
            int i0, i1; float wi;
            coord16(ci, i0, i1, wi);
            float av[4], kv[4];
            #pragma unroll
            for (int u = 0; u < 4; ++u) {
                int gj = oj + c4 + u;
                int cj = gj < 1 ? 1 : (gj > GN - 2 ? GN - 2 : gj);
                int j0, j1; float wj;
                coord16(cj, j0, j1, wj);
                av[u] = bilin16(Aarg, i0, i1, wi, j0, j1, wj) * 0.1046529f;
                kv[u] = bilin16(Karg, i0, i1, wi, j0, j1, wj) * 5.115e-5f;
            }
            a2[q] = make_float4(av[0], av[1], av[2], av[3]);
            k2[q] = make_float4(kv[0], kv[1], kv[2], kv[3]);
        }
    }

    float4 V[4];
    {
        float4 ld0 = *(const float4*)(srcp + gbase);
        float4 ld1 = *(const float4*)(srcp + gbase + GN);
        float4 ld2 = *(const float4*)(srcp + gbase + 2 * GN);
        float4 ld3 = *(const float4*)(srcp + gbase + 3 * GN);
        *(float4*)&lds[0][w0off]  = ld0;
        *(float4*)&lds[0][w3off]  = ld3;
        *(float4*)&lds[0][wsloff] = make_float4(ld0.w, ld1.w, ld2.w, ld3.w);
        *(float4*)&lds[0][wsroff] = make_float4(ld0.x, ld1.x, ld2.x, ld3.x);
        V[0] = istop ? ld1 : ld0;
        V[1] = ld1;
        V[2] = ld2;
        V[3] = isbot ? ld2 : ld3;
    }
    __syncthreads();

    #pragma unroll 1
    for (int it = 0; it < KST / 2; ++it) {
        #pragma unroll
        for (int half = 0; half < 2; ++half) {
            const int t = 2 * it + 1 + half;
            const float* cur = half ? &lds[1][0] : &lds[0][0];
            float*       nxt = half ? &lds[0][0] : &lds[1][0];

            float4 U  = *(const float4*)(cur + uoff);
            float4 D  = *(const float4*)(cur + doff);
            float4 SL = *(const float4*)(cur + sloff);
            float4 SR = *(const float4*)(cur + sroff);

            float4 Uop1 = istop ? U : V[0];
            float4 Dop2 = isbot ? D : V[3];

            float4 NV0 = rowcell(V[0], U,    V[1], SL.x, SR.x, a2[0], k2[0], isl, isr);
            float4 NV1 = rowcell(V[1], Uop1, V[2], SL.y, SR.y, a2[1], k2[1], isl, isr);
            float4 NV2 = rowcell(V[2], V[1], Dop2, SL.z, SR.z, a2[2], k2[2], isl, isr);
            float4 NV3 = rowcell(V[3], V[2], D,    SL.w, SR.w, a2[3], k2[3], isl, isr);
            if (istop) NV0 = NV1;
            if (isbot) NV3 = NV2;

            *(float4*)(nxt + w0off)  = NV0;
            *(float4*)(nxt + w3off)  = NV3;
            *(float4*)(nxt + wsloff) = make_float4(NV0.w, NV1.w, NV2.w, NV3.w);
            *(float4*)(nxt + wsroff) = make_float4(NV0.x, NV1.x, NV2.x, NV3.x);

            if (core && t <= tmax) {
                float* slab = out + (long)(base + t - 1) * GNN;
                *(float4*)(slab + gbase)          = NV0;
                *(float4*)(slab + gbase + GN)     = NV1;
                *(float4*)(slab + gbase + 2 * GN) = NV2;
                *(float4*)(slab + gbase + 3 * GN) = NV3;
            }
            V[0] = NV0; V[1] = NV1; V[2] = NV2; V[3] = NV3;
            lds_barrier();
        }
    }
}

extern "C" void kernel_launch(void* const* d_in, const int* in_sizes, int n_in,
                              void* d_out, int out_size, void* d_ws, size_t ws_size,
                              hipStream_t stream) {
    const float* u0    = (const float*)d_in[0];
    const float* alpha = (const float*)d_in[1];
    const float* kappa = (const float*)d_in[2];
    float* out = (float*)d_out;

    dim3 grd(GN / TILE, GN / TILE, 1);   // 16x16 = 256 blocks = 1/CU
    dim3 blk(NTHR, 1, 1);

    int dev = 0;
    hipGetDevice(&dev);
    int coop = 0;
    hipDeviceGetAttribute(&coop, hipDeviceAttributeCooperativeLaunch, dev);

    if (coop) {
        void* args[] = {(void*)&u0, (void*)&alpha, (void*)&kappa, (void*)&out};
        hipError_t e = hipLaunchCooperativeKernel((void*)coop_steps_kernel,
                                                  grd, blk, args, 0, stream);
        if (e == hipSuccess) return;
    }

    // Fallback: verified round-7 relaunch path.
    bool use_ws = ws_size >= (size_t)2 * GNN * sizeof(float);
    if (use_ws) {
        float* a2map = (float*)d_ws;
        float* k2map = a2map + GNN;
        resize_maps_kernel<<<(GNN + 255) / 256, 256, 0, stream>>>(alpha, kappa, a2map, k2map);
        for (int b = 0; b < NOUT; b += KST) {
            const float* src = (b == 0) ? u0 : out + (long)(b - 1) * GNN;
            fused_steps_kernel<true><<<grd, blk, 0, stream>>>(src, a2map, k2map, out, b);
        }
    } else {
        for (int b = 0; b < NOUT; b += KST) {
            const float* src = (b == 0) ? u0 : out + (long)(b - 1) * GNN;
            fused_steps_kernel<false><<<grd, blk, 0, stream>>>(src, alpha, kappa, out, b);
        }
    }
}

// Round 9
// 247.359 us; speedup vs baseline: 3.7593x; 3.7593x over previous
//
#include <hip/hip_runtime.h>

#define GN   1024
#define GNN  (GN * GN)
#define GP   16
#define NOUT 127          // ys[1:] = T_1 .. T_127
#define TI   64           // output tile rows per block
#define TJ   32           // output tile cols per block
#define KH   16           // halo depth = fused steps per launch
#define SZI  96           // region rows  (TI + 2*KH)
#define SZJ  64           // region cols  (TJ + 2*KH)
#define NRB  24           // row-blocks  (SZI/4)
#define NCB  16           // col-blocks  (SZJ/4)
#define NTHR 384          // NRB*NCB, 6 waves
#define RST  68           // row-plane stride (floats), 4-aligned
#define AST  100          // aux col-slot stride (>= NRB*4 = 96), 4-aligned
#define AXB  (NRB * 2 * RST)        // 3264
#define AXS  ((NCB + 1) * AST)      // 1700 per side
#define PLN  (AXB + 2 * AXS)        // 6664 floats = 26.7 KB/plane

// Exact fp32 constants: DT/dx^2 = 1e-7*1023^2 = 0.1046529, DT/(2dx) = 5.115e-5

__device__ __forceinline__ void coord16(int t, int& c0, int& c1, float& w) {
    // coords = linspace(0, 15, 1024): c = t * 15/1023
    double c = (double)t * (15.0 / 1023.0);
    c0 = (int)c;
    c1 = c0 + 1 > 15 ? 15 : c0 + 1;
    w  = (float)(c - (double)c0);
}

__device__ __forceinline__ float bilin16(const float* __restrict__ m,
                                         int i0, int i1, float wi,
                                         int j0, int j1, float wj) {
    float m00 = m[i0 * GP + j0];
    float m10 = m[i1 * GP + j0];
    float m01 = m[i0 * GP + j1];
    float m11 = m[i1 * GP + j1];
    float r0 = m00 * (1.0f - wi) + m10 * wi;
    float r1 = m01 * (1.0f - wi) + m11 * wi;
    return r0 * (1.0f - wj) + r1 * wj;
}

__device__ __forceinline__ float cellv(float C, float L, float R, float U, float D,
                                       float a2, float k2) {
    // val = C - k2*C*((D-U)+(R-L)) + a2*(U+D+L+R-4C)
    float s   = (D - U) + (R - L);
    float lap = fmaf(-4.0f, C, (U + D) + (L + R));
    return fmaf(a2, lap, fmaf(-k2, C * s, C));
}

// One 4-wide row of cells: verified column shift-select logic (rounds 4-7).
__device__ __forceinline__ float4 rowcell(float4 v, float4 U, float4 D,
                                          float sl, float sr,
                                          float4 a2, float4 k2,
                                          bool isl, bool isr) {
    float L0 = isl ? v.x : sl;
    float C0 = isl ? v.y : v.x;
    float R0 = isl ? v.z : v.y;
    float U0 = isl ? U.y : U.x;
    float D0 = isl ? D.y : D.x;
    float L3 = isr ? v.y : v.z;
    float C3 = isr ? v.z : v.w;
    float R3 = isr ? v.w : sr;
    float U3 = isr ? U.z : U.w;
    float D3 = isr ? D.z : D.w;
    float4 nv;
    nv.x = cellv(C0,  L0,  R0,  U0,  D0,  a2.x, k2.x);
    nv.y = cellv(v.y, v.x, v.z, U.y, D.y, a2.y, k2.y);
    nv.z = cellv(v.z, v.y, v.w, U.z, D.z, a2.z, k2.z);
    nv.w = cellv(C3,  L3,  R3,  U3,  D3,  a2.w, k2.w);
    return nv;
}

// LDS-only barrier (global stores stay in flight; rule #18 fencing).
__device__ __forceinline__ void lds_barrier() {
    __builtin_amdgcn_sched_barrier(0);
    asm volatile("s_waitcnt lgkmcnt(0)" ::: "memory");
    __builtin_amdgcn_s_barrier();
    __builtin_amdgcn_sched_barrier(0);
}

// Temporal-blocked stepper, stale-halo scheme (verified rounds 4-7), now
// 64x32 output tiles -> 512 blocks = 2 blocks/CU (LDS 2x26.7KB = 53.3KB/block,
// 106.6KB for two blocks < 160KB). Two co-resident blocks desynchronize the
// per-step store burst / barrier wait, keeping the HBM write stream busy.
// Coefficients are computed inline once per launch (16x16 tables are
// L1-resident); src loads are issued first so their latency hides under the
// coefficient VALU.
__global__ __launch_bounds__(NTHR, 3)
void fused_steps_kernel(const float* __restrict__ srcp,
                        const float* __restrict__ alpha,
                        const float* __restrict__ kappa,
                        float* __restrict__ out,
                        int base)
{
    __shared__ float lds[2][PLN];   // 2 x 26.7 KB

    const int tid = threadIdx.x;
    const int rb  = tid >> 4;          // tid / NCB
    const int cb  = tid & (NCB - 1);
    const int r0  = rb * 4;
    const int c4  = cb * 4;

    const int gi0 = blockIdx.y * TI;
    const int gj0 = blockIdx.x * TJ;
    int oi = gi0 - KH; oi = oi < 0 ? 0 : (oi > GN - SZI ? GN - SZI : oi);
    int oj = gj0 - KH; oj = oj < 0 ? 0 : (oj > GN - SZJ ? GN - SZJ : oj);
    const int di = gi0 - oi;           // 0, 16, or 32
    const int dj = gj0 - oj;           // 0, 16, or 32

    const bool istop = (rb == 0), isbot = (rb == NRB - 1);
    const bool isl   = (cb == 0), isr   = (cb == NCB - 1);
    const bool core  = (rb >= (di >> 2)) && (rb < (di >> 2) + TI / 4)
                    && (cb >= (dj >> 2)) && (cb < (dj >> 2) + TJ / 4);
    const int  tmax  = NOUT - base;

    const long gbase = (long)(oi + r0) * GN + oj + c4;

    // Plane-relative float offsets (row plane stride RST, aux stride AST)
    const int uoff   = (istop ? 0 : (rb * 2 - 1)) * RST + c4;
    const int doff   = (isbot ? (NRB * 2 - 1) : (rb * 2 + 2)) * RST + c4;
    const int w0off  = (rb * 2) * RST + c4;
    const int w3off  = (rb * 2 + 1) * RST + c4;
    const int sloff  = AXB + cb * AST + r0;            // read: left nb .w col
    const int wsloff = AXB + (cb + 1) * AST + r0;      // write: own .w col
    const int sroff  = AXB + AXS + (cb + 1) * AST + r0;// read: right nb .x col
    const int wsroff = AXB + AXS + cb * AST + r0;      // write: own .x col

    // Issue src loads first (latency hides under coefficient VALU below).
    float4 ld0 = *(const float4*)(srcp + gbase);
    float4 ld1 = *(const float4*)(srcp + gbase + GN);
    float4 ld2 = *(const float4*)(srcp + gbase + 2 * GN);
    float4 ld3 = *(const float4*)(srcp + gbase + 3 * GN);

    // Inline clamp-baked, pre-scaled coefficients (computed once per launch).
    float4 a2[4], k2[4];
    {
        int j0[4], j1[4]; float wj[4];
        #pragma unroll
        for (int u = 0; u < 4; ++u) {
            int gj = oj + c4 + u;
            int cj = gj < 1 ? 1 : (gj > GN - 2 ? GN - 2 : gj);
            coord16(cj, j0[u], j1[u], wj[u]);
        }
        #pragma unroll
        for (int q = 0; q < 4; ++q) {
            int gi = oi + r0 + q;
            int ci = gi < 1 ? 1 : (gi > GN - 2 ? GN - 2 : gi);
            int i0, i1; float wi;
            coord16(ci, i0, i1, wi);
            float av[4], kv[4];
            #pragma unroll
            for (int u = 0; u < 4; ++u) {
                av[u] = bilin16(alpha, i0, i1, wi, j0[u], j1[u], wj[u]) * 0.1046529f;
                kv[u] = bilin16(kappa, i0, i1, wi, j0[u], j1[u], wj[u]) * 5.115e-5f;
            }
            a2[q] = make_float4(av[0], av[1], av[2], av[3]);
            k2[q] = make_float4(kv[0], kv[1], kv[2], kv[3]);
        }
    }

    // Seed: raw rows to LDS plane 0; CLAMPED rows to register carry
    // (verified round-4 semantics: replica row-blocks carry the adjacent
    // genuine row so their stencil is operand-identical to it).
    *(float4*)&lds[0][w0off]  = ld0;
    *(float4*)&lds[0][w3off]  = ld3;
    *(float4*)&lds[0][wsloff] = make_float4(ld0.w, ld1.w, ld2.w, ld3.w);
    *(float4*)&lds[0][wsroff] = make_float4(ld0.x, ld1.x, ld2.x, ld3.x);
    float4 V[4];
    V[0] = istop ? ld1 : ld0;
    V[1] = ld1;
    V[2] = ld2;
    V[3] = isbot ? ld2 : ld3;
    __syncthreads();

    #pragma unroll 1
    for (int it = 0; it < KH / 2; ++it) {
        #pragma unroll
        for (int half = 0; half < 2; ++half) {
            const int t = 2 * it + 1 + half;
            const float* cur = half ? &lds[1][0] : &lds[0][0];
            float*       nxt = half ? &lds[0][0] : &lds[1][0];

            float4 U  = *(const float4*)(cur + uoff);
            float4 D  = *(const float4*)(cur + doff);
            float4 SL = *(const float4*)(cur + sloff);   // rows 0..3 left scalars
            float4 SR = *(const float4*)(cur + sroff);   // rows 0..3 right scalars

            float4 Uop1 = istop ? U : V[0];
            float4 Dop2 = isbot ? D : V[3];

            float4 NV0 = rowcell(V[0], U,    V[1], SL.x, SR.x, a2[0], k2[0], isl, isr);
            float4 NV1 = rowcell(V[1], Uop1, V[2], SL.y, SR.y, a2[1], k2[1], isl, isr);
            float4 NV2 = rowcell(V[2], V[1], Dop2, SL.z, SR.z, a2[2], k2[2], isl, isr);
            float4 NV3 = rowcell(V[3], V[2], D,    SL.w, SR.w, a2[3], k2[3], isl, isr);
            if (istop) NV0 = NV1;             // replica rows
            if (isbot) NV3 = NV2;

            *(float4*)(nxt + w0off)  = NV0;
            *(float4*)(nxt + w3off)  = NV3;
            *(float4*)(nxt + wsloff) = make_float4(NV0.w, NV1.w, NV2.w, NV3.w);
            *(float4*)(nxt + wsroff) = make_float4(NV0.x, NV1.x, NV2.x, NV3.x);

            if (core && t <= tmax) {
                float* slab = out + (long)(base + t - 1) * GNN;
                *(float4*)(slab + gbase)          = NV0;
                *(float4*)(slab + gbase + GN)     = NV1;
                *(float4*)(slab + gbase + 2 * GN) = NV2;
                *(float4*)(slab + gbase + 3 * GN) = NV3;
            }
            V[0] = NV0; V[1] = NV1; V[2] = NV2; V[3] = NV3;
            lds_barrier();   // DS-only wait: global stores keep draining async
        }
    }
}

extern "C" void kernel_launch(void* const* d_in, const int* in_sizes, int n_in,
                              void* d_out, int out_size, void* d_ws, size_t ws_size,
                              hipStream_t stream) {
    const float* u0    = (const float*)d_in[0];
    const float* alpha = (const float*)d_in[1];
    const float* kappa = (const float*)d_in[2];
    float* out = (float*)d_out;

    dim3 grd(GN / TJ, GN / TI, 1);   // 32 x 16 = 512 blocks = 2/CU
    dim3 blk(NTHR, 1, 1);

    for (int b = 0; b < NOUT; b += KH) {
        const float* src = (b == 0) ? u0 : out + (long)(b - 1) * GNN;
        fused_steps_kernel<<<grd, blk, 0, stream>>>(src, alpha, kappa, out, b);
    }
}

// Round 10
// 207.080 us; speedup vs baseline: 4.4905x; 1.1945x over previous
//
#include <hip/hip_runtime.h>

#define GN   1024
#define GNN  (GN * GN)
#define GP   16
#define NOUT 127          // ys[1:] = T_1 .. T_127
#define TI   64           // output tile side
#define KH   16           // halo depth = max fused steps per launch
#define SZI  96           // region side (TI + 2*KH)
#define NRB  24           // row-blocks  (SZI/4)
#define NCB  24           // col-blocks  (SZI/4)
#define NTHR 576          // NRB*NCB threads, 9 waves
#define RST  100          // row-plane stride (floats), 4-aligned
#define AXB  (NRB * 2 * RST)            // aux base within plane = 4800
#define AXS  ((NCB + 1) * RST)          // one aux side = 2500
#define PLN  (AXB + 2 * AXS)            // plane floats = 9800 (39.2 KB)

// Exact fp32 constants: DT/dx^2 = 1e-7*1023^2 = 0.1046529, DT/(2dx) = 5.115e-5

__device__ __forceinline__ void coord16(int t, int& c0, int& c1, float& w) {
    // coords = linspace(0, 15, 1024): c = t * 15/1023
    double c = (double)t * (15.0 / 1023.0);
    c0 = (int)c;
    c1 = c0 + 1 > 15 ? 15 : c0 + 1;
    w  = (float)(c - (double)c0);
}

__device__ __forceinline__ float bilin16(const float* __restrict__ m,
                                         int i0, int i1, float wi,
                                         int j0, int j1, float wj) {
    float m00 = m[i0 * GP + j0];
    float m10 = m[i1 * GP + j0];
    float m01 = m[i0 * GP + j1];
    float m11 = m[i1 * GP + j1];
    float r0 = m00 * (1.0f - wi) + m10 * wi;
    float r1 = m01 * (1.0f - wi) + m11 * wi;
    return r0 * (1.0f - wj) + r1 * wj;
}

__device__ __forceinline__ float cellv(float C, float L, float R, float U, float D,
                                       float a2, float k2) {
    // val = C - k2*C*((D-U)+(R-L)) + a2*(U+D+L+R-4C)
    float s   = (D - U) + (R - L);
    float lap = fmaf(-4.0f, C, (U + D) + (L + R));
    return fmaf(a2, lap, fmaf(-k2, C * s, C));
}

// One 4-wide row of cells: verified column shift-select logic (rounds 4-7).
__device__ __forceinline__ float4 rowcell(float4 v, float4 U, float4 D,
                                          float sl, float sr,
                                          float4 a2, float4 k2,
                                          bool isl, bool isr) {
    float L0 = isl ? v.x : sl;
    float C0 = isl ? v.y : v.x;
    float R0 = isl ? v.z : v.y;
    float U0 = isl ? U.y : U.x;
    float D0 = isl ? D.y : D.x;
    float L3 = isr ? v.y : v.z;
    float C3 = isr ? v.z : v.w;
    float R3 = isr ? v.w : sr;
    float U3 = isr ? U.z : U.w;
    float D3 = isr ? D.z : D.w;
    float4 nv;
    nv.x = cellv(C0,  L0,  R0,  U0,  D0,  a2.x, k2.x);
    nv.y = cellv(v.y, v.x, v.z, U.y, D.y, a2.y, k2.y);
    nv.z = cellv(v.z, v.y, v.w, U.z, D.z, a2.z, k2.z);
    nv.w = cellv(C3,  L3,  R3,  U3,  D3,  a2.w, k2.w);
    return nv;
}

// LDS-only barrier (global stores stay in flight; rule #18 fencing).
__device__ __forceinline__ void lds_barrier() {
    __builtin_amdgcn_sched_barrier(0);
    asm volatile("s_waitcnt lgkmcnt(0)" ::: "memory");
    __builtin_amdgcn_s_barrier();
    __builtin_amdgcn_sched_barrier(0);
}

// Clamp-baked, pre-scaled coefficient maps.
__global__ __launch_bounds__(256)
void resize_maps_kernel(const float* __restrict__ alpha,
                        const float* __restrict__ kappa,
                        float* __restrict__ a2map,
                        float* __restrict__ k2map) {
    int idx = blockIdx.x * 256 + threadIdx.x;
    if (idx >= GNN) return;
    int i = idx >> 10;
    int j = idx & (GN - 1);
    int ci = i < 1 ? 1 : (i > GN - 2 ? GN - 2 : i);
    int cj = j < 1 ? 1 : (j > GN - 2 ? GN - 2 : j);
    int i0, i1, j0, j1; float wi, wj;
    coord16(ci, i0, i1, wi);
    coord16(cj, j0, j1, wj);
    a2map[idx] = bilin16(alpha, i0, i1, wi, j0, j1, wj) * 0.1046529f;
    k2map[idx] = bilin16(kappa, i0, i1, wi, j0, j1, wj) * 5.115e-5f;
}

// Temporal-blocked stepper, stale-halo scheme (verified rounds 4-7), plus
// row-window staleness skip: at step t only rows within (KH - t) of the core
// can still influence it; thread row-blocks fully outside
// [di-(KH-t), di+TI-1+(KH-t)] skip all work (barrier still hit). Physical-
// boundary sides never shrink (di=0 / ahi pinned at SZI-1 there), so replica
// rows stay live. Exactness: W(t)+-1 subset W(t-1) = active(t-1), so every
// operand an in-window cell reads was written last step.
template <bool USE_WS>
__global__ __launch_bounds__(NTHR)
void fused_steps_kernel(const float* __restrict__ srcp,
                        const float* __restrict__ Aarg,   // a2map or alpha
                        const float* __restrict__ Karg,   // k2map or kappa
                        float* __restrict__ out,
                        int base)
{
    __shared__ float lds[2][PLN];   // 2 x 39.2 KB

    const int tid = threadIdx.x;
    const int rb  = tid / NCB;
    const int cb  = tid - rb * NCB;
    const int r0  = rb * 4;
    const int c4  = cb * 4;

    const int gi0 = blockIdx.y * TI;
    const int gj0 = blockIdx.x * TI;
    int oi = gi0 - KH; oi = oi < 0 ? 0 : (oi > GN - SZI ? GN - SZI : oi);
    int oj = gj0 - KH; oj = oj < 0 ? 0 : (oj > GN - SZI ? GN - SZI : oj);
    const int di = gi0 - oi;           // 0, 16, or 32
    const int dj = gj0 - oj;

    const bool istop = (rb == 0), isbot = (rb == NRB - 1);
    const bool isl   = (cb == 0), isr   = (cb == NCB - 1);
    const bool core  = (rb >= (di >> 2)) && (rb < (di >> 2) + TI / 4)
                    && (cb >= (dj >> 2)) && (cb < (dj >> 2) + TI / 4);
    const int  tmax  = NOUT - base;
    const int  kk    = tmax < KH ? tmax : KH;   // steps this launch

    const long gbase = (long)(oi + r0) * GN + oj + c4;

    const int uoff   = (istop ? 0 : (rb * 2 - 1)) * RST + c4;
    const int doff   = (isbot ? (NRB * 2 - 1) : (rb * 2 + 2)) * RST + c4;
    const int w0off  = (rb * 2) * RST + c4;
    const int w3off  = (rb * 2 + 1) * RST + c4;
    const int sloff  = AXB + cb * RST + rb * 4;
    const int wsloff = AXB + (cb + 1) * RST + rb * 4;
    const int sroff  = AXB + AXS + (cb + 1) * RST + rb * 4;
    const int wsroff = AXB + AXS + cb * RST + rb * 4;

    float4 a2[4], k2[4];
    if (USE_WS) {
        #pragma unroll
        for (int q = 0; q < 4; ++q) {
            a2[q] = *(const float4*)(Aarg + gbase + q * GN);
            k2[q] = *(const float4*)(Karg + gbase + q * GN);
        }
    } else {
        #pragma unroll
        for (int q = 0; q < 4; ++q) {
            int gi = oi + r0 + q;
            int ci = gi < 1 ? 1 : (gi > GN - 2 ? GN - 2 : gi);
            int i0, i1; float wi;
            coord16(ci, i0, i1, wi);
            float av[4], kv[4];
            #pragma unroll
            for (int u = 0; u < 4; ++u) {
                int gj = oj + c4 + u;
                int cj = gj < 1 ? 1 : (gj > GN - 2 ? GN - 2 : gj);
                int j0, j1; float wj;
                coord16(cj, j0, j1, wj);
                av[u] = bilin16(Aarg, i0, i1, wi, j0, j1, wj) * 0.1046529f;
                kv[u] = bilin16(Karg, i0, i1, wi, j0, j1, wj) * 5.115e-5f;
            }
            a2[q] = make_float4(av[0], av[1], av[2], av[3]);
            k2[q] = make_float4(kv[0], kv[1], kv[2], kv[3]);
        }
    }

    // Seed: raw rows to LDS plane 0; CLAMPED rows to register carry.
    float4 V[4];
    {
        float4 ld0 = *(const float4*)(srcp + gbase);
        float4 ld1 = *(const float4*)(srcp + gbase + GN);
        float4 ld2 = *(const float4*)(srcp + gbase + 2 * GN);
        float4 ld3 = *(const float4*)(srcp + gbase + 3 * GN);
        *(float4*)&lds[0][w0off]  = ld0;
        *(float4*)&lds[0][w3off]  = ld3;
        *(float4*)&lds[0][wsloff] = make_float4(ld0.w, ld1.w, ld2.w, ld3.w);
        *(float4*)&lds[0][wsroff] = make_float4(ld0.x, ld1.x, ld2.x, ld3.x);
        V[0] = istop ? ld1 : ld0;
        V[1] = ld1;
        V[2] = ld2;
        V[3] = isbot ? ld2 : ld3;
    }
    __syncthreads();

    const float* cur = &lds[0][0];
    float*       nxt = &lds[1][0];
    const int ahi_s = di + TI - 1;     // core row range [di, ahi_s]

    #pragma unroll 1
    for (int t = 1; t <= kk; ++t) {
        const int marg = KH - t;
        int alo = di - marg;      if (alo < 0) alo = 0;
        int ahi = ahi_s + marg;   if (ahi > SZI - 1) ahi = SZI - 1;

        if (r0 + 3 >= alo && r0 <= ahi) {
            float4 U  = *(const float4*)(cur + uoff);
            float4 D  = *(const float4*)(cur + doff);
            float4 SL = *(const float4*)(cur + sloff);
            float4 SR = *(const float4*)(cur + sroff);

            float4 Uop1 = istop ? U : V[0];
            float4 Dop2 = isbot ? D : V[3];

            float4 NV0 = rowcell(V[0], U,    V[1], SL.x, SR.x, a2[0], k2[0], isl, isr);
            float4 NV1 = rowcell(V[1], Uop1, V[2], SL.y, SR.y, a2[1], k2[1], isl, isr);
            float4 NV2 = rowcell(V[2], V[1], Dop2, SL.z, SR.z, a2[2], k2[2], isl, isr);
            float4 NV3 = rowcell(V[3], V[2], D,    SL.w, SR.w, a2[3], k2[3], isl, isr);
            if (istop) NV0 = NV1;             // replica rows
            if (isbot) NV3 = NV2;

            *(float4*)(nxt + w0off)  = NV0;
            *(float4*)(nxt + w3off)  = NV3;
            *(float4*)(nxt + wsloff) = make_float4(NV0.w, NV1.w, NV2.w, NV3.w);
            *(float4*)(nxt + wsroff) = make_float4(NV0.x, NV1.x, NV2.x, NV3.x);

            if (core) {
                float* slab = out + (long)(base + t - 1) * GNN;
                *(float4*)(slab + gbase)          = NV0;
                *(float4*)(slab + gbase + GN)     = NV1;
                *(float4*)(slab + gbase + 2 * GN) = NV2;
                *(float4*)(slab + gbase + 3 * GN) = NV3;
            }
            V[0] = NV0; V[1] = NV1; V[2] = NV2; V[3] = NV3;
        }
        lds_barrier();   // DS-only wait: global stores keep draining async

        const float* tmp = cur; cur = nxt; nxt = (float*)tmp;
    }
}

extern "C" void kernel_launch(void* const* d_in, const int* in_sizes, int n_in,
                              void* d_out, int out_size, void* d_ws, size_t ws_size,
                              hipStream_t stream) {
    const float* u0    = (const float*)d_in[0];
    const float* alpha = (const float*)d_in[1];
    const float* kappa = (const float*)d_in[2];
    float* out = (float*)d_out;

    dim3 grd(GN / TI, GN / TI, 1);   // 16x16 = 256 blocks = 1/CU
    dim3 blk(NTHR, 1, 1);

    bool use_ws = ws_size >= (size_t)2 * GNN * sizeof(float);

    if (use_ws) {
        float* a2map = (float*)d_ws;
        float* k2map = a2map + GNN;
        resize_maps_kernel<<<(GNN + 255) / 256, 256, 0, stream>>>(alpha, kappa, a2map, k2map);
        for (int b = 0; b < NOUT; b += KH) {
            const float* src = (b == 0) ? u0 : out + (long)(b - 1) * GNN;
            fused_steps_kernel<true><<<grd, blk, 0, stream>>>(src, a2map, k2map, out, b);
        }
    } else {
        for (int b = 0; b < NOUT; b += KH) {
            const float* src = (b == 0) ? u0 : out + (long)(b - 1) * GNN;
            fused_steps_kernel<false><<<grd, blk, 0, stream>>>(src, alpha, kappa, out, b);
        }
    }
}